// Round 1
// baseline (3679.461 us; speedup 1.0000x reference)
//
#include <hip/hip_runtime.h>
#include <cstdint>
#include <cstddef>

#define Vv 32000
#define Ee 256
#define Hh 256
#define Bb 4
#define Tt 512
#define Mm (Bb*Tt)   // 2048

// ---------------------------------------------------------------------------
// Small GEMM: C[M,N] = A[M,256] @ W[N,256]^T + bias ; A optionally gathered
// from embedding table via row indices. Tiles: 32(M) x 64(N), KC=64.
// ---------------------------------------------------------------------------
template<bool GATHER>
__global__ __launch_bounds__(256) void gemm_small(
    const float* __restrict__ A, const int* __restrict__ xidx,
    const float* __restrict__ W, const float* __restrict__ bias,
    float* __restrict__ C, int N)
{
  __shared__ float At[64][36];   // [k][m], pad 36 -> fp4-aligned, conflict-free
  __shared__ float Wt[64][66];   // [k][n], pad 66 -> fp2-aligned, 2-way max
  const int tid = threadIdx.x;
  const int m0 = blockIdx.x * 32;
  const int n0 = blockIdx.y * 64;
  const int tm = tid >> 5;       // 0..7   (4 m each)
  const int tn = tid & 31;       // 0..31  (2 n each)
  float acc[4][2] = {};

  for (int k0 = 0; k0 < 256; k0 += 64) {
    __syncthreads();
    // stage A: 32 rows x 64 k = 512 float4
    #pragma unroll
    for (int r = 0; r < 2; ++r) {
      int idx = tid + r*256;
      int i  = idx >> 4;          // row 0..31
      int c4 = idx & 15;          // float4 col
      const float* src;
      if (GATHER) src = A + (size_t)xidx[m0+i]*256 + k0 + c4*4;
      else        src = A + (size_t)(m0+i)*256 + k0 + c4*4;
      float4 v = *(const float4*)src;
      At[c4*4+0][i]=v.x; At[c4*4+1][i]=v.y; At[c4*4+2][i]=v.z; At[c4*4+3][i]=v.w;
    }
    // stage W: 64 rows x 64 k = 1024 float4
    #pragma unroll
    for (int r = 0; r < 4; ++r) {
      int idx = tid + r*256;
      int j  = idx >> 4;
      int c4 = idx & 15;
      float4 v = *(const float4*)(W + (size_t)(n0+j)*256 + k0 + c4*4);
      Wt[c4*4+0][j]=v.x; Wt[c4*4+1][j]=v.y; Wt[c4*4+2][j]=v.z; Wt[c4*4+3][j]=v.w;
    }
    __syncthreads();
    #pragma unroll 8
    for (int k = 0; k < 64; ++k) {
      float4 a = *(const float4*)&At[k][tm*4];
      float2 w = *(const float2*)&Wt[k][tn*2];
      acc[0][0] += a.x*w.x; acc[0][1] += a.x*w.y;
      acc[1][0] += a.y*w.x; acc[1][1] += a.y*w.y;
      acc[2][0] += a.z*w.x; acc[2][1] += a.z*w.y;
      acc[3][0] += a.w*w.x; acc[3][1] += a.w*w.y;
    }
  }
  #pragma unroll
  for (int i = 0; i < 4; ++i)
    #pragma unroll
    for (int j = 0; j < 2; ++j) {
      int m = m0 + tm*4 + i, n = n0 + tn*2 + j;
      C[(size_t)m*N + n] = acc[i][j] + bias[n];
    }
}

// ---------------------------------------------------------------------------
// GRU scan: persistent kernel, 32 blocks x 192 threads.
// block = (batch-pair p = bid>>4, j-chunk c = bid&15 of 16 j's).
// Holds w_hh rows {g*256 + c*16 + j'} (48 rows) in LDS. One device-scope
// barrier per timestep; h_t broadcast through the `gout` buffer.
// ---------------------------------------------------------------------------
__global__ __launch_bounds__(192) void gru_scan(
    const float* __restrict__ xp, const float* __restrict__ h0,
    const float* __restrict__ whh, const float* __restrict__ bhh,
    float* __restrict__ gout, unsigned int* __restrict__ bar)
{
  __shared__ __attribute__((aligned(16))) float wl[48][260];     // pad: 2-way max
  __shared__ __attribute__((aligned(16))) float hrep[4][2][260]; // per-kq replica: conflict-free
  __shared__ float dl[48][2];

  const int tid = threadIdx.x;
  const int bid = blockIdx.x;
  const int c = bid & 15;   // j-chunk (16 j's)
  const int p = bid >> 4;   // batch pair {2p, 2p+1}

  // load weights once: 48 rows x 64 float4 = 3072 float4 / 192 thr = 16 each
  #pragma unroll
  for (int it = 0; it < 16; ++it) {
    int idx = tid + it*192;
    int row = idx >> 6;          // 0..47
    int c4  = idx & 63;
    int g = row >> 4, jl = row & 15;
    int grow = g*256 + c*16 + jl;
    float4 v = *(const float4*)(whh + (size_t)grow*256 + c4*4);
    *(float4*)&wl[row][c4*4] = v;
  }
  __syncthreads();

  const int r  = tid >> 2;   // 0..47
  const int kq = tid & 3;
  const int k0 = kq * 64;

  for (int t = 0; t < Tt; ++t) {
    // stage h_{t-1} (4 replicated copies x 2 batches x 256)
    #pragma unroll
    for (int it = 0; it < 3; ++it) {
      int idx = tid + it*192;
      if (idx < 512) {
        int copy = idx >> 7;
        int rem  = idx & 127;
        int b2   = rem >> 6;
        int c4   = rem & 63;
        int b    = p*2 + b2;
        const float* hsrc = (t == 0) ? (h0 + b*Hh)
                                     : (gout + ((size_t)(b*Tt) + (t-1))*Hh);
        float4 v = *(const float4*)(hsrc + c4*4);
        *(float4*)&hrep[copy][b2][c4*4] = v;
      }
    }
    __syncthreads();

    // partial dots: thread (r, kq) -> 64 k's for 2 batches
    float s0 = 0.f, s1 = 0.f;
    {
      const float* wr  = &wl[r][k0];
      const float* hp0 = &hrep[kq][0][k0];
      const float* hp1 = &hrep[kq][1][k0];
      #pragma unroll
      for (int kk = 0; kk < 16; ++kk) {
        float4 wv = *(const float4*)(wr  + kk*4);
        float4 a  = *(const float4*)(hp0 + kk*4);
        float4 b  = *(const float4*)(hp1 + kk*4);
        s0 += wv.x*a.x + wv.y*a.y + wv.z*a.z + wv.w*a.w;
        s1 += wv.x*b.x + wv.y*b.y + wv.z*b.z + wv.w*b.w;
      }
    }
    s0 += __shfl_xor(s0, 1); s0 += __shfl_xor(s0, 2);
    s1 += __shfl_xor(s1, 1); s1 += __shfl_xor(s1, 2);
    if (kq == 0) { dl[r][0] = s0; dl[r][1] = s1; }
    __syncthreads();

    // gate combine + h update: 32 threads (16 j x 2 batches)
    if (tid < 32) {
      int b2 = tid >> 4, jl = tid & 15;
      float dr = dl[jl][b2], dz = dl[16+jl][b2], dn = dl[32+jl][b2];
      int b  = p*2 + b2;
      int jg = c*16 + jl;
      size_t xb = ((size_t)(b*Tt) + t)*768 + jg;
      float xr = xp[xb], xz = xp[xb+256], xn = xp[xb+512];
      float rr = 1.f/(1.f + __expf(-(xr + dr + bhh[jg])));
      float zz = 1.f/(1.f + __expf(-(xz + dz + bhh[256+jg])));
      float aa = xn + rr*(dn + bhh[512+jg]);
      float nn = 1.f - 2.f/(1.f + __expf(2.f*aa));     // tanh, exact formula
      float hp = hrep[0][b2][jg];
      float hn = (1.f - zz)*nn + zz*hp;
      gout[((size_t)(b*Tt) + t)*Hh + jg] = hn;
    }
    __threadfence();          // agent-scope: drain stores, wb L2
    __syncthreads();
    if (tid == 0) {
      __hip_atomic_fetch_add(bar, 1u, __ATOMIC_RELEASE, __HIP_MEMORY_SCOPE_AGENT);
      unsigned int tgt = 32u*(unsigned)(t+1);
      while (__hip_atomic_load(bar, __ATOMIC_ACQUIRE, __HIP_MEMORY_SCOPE_AGENT) < tgt) {
        __builtin_amdgcn_s_sleep(1);
      }
    }
    __syncthreads();
  }
}

// ---------------------------------------------------------------------------
// Attention: one block per (b, i). scores_j = v . tanh(q_i + k_j) + vb (j<=i),
// softmax, ctx_i = sum_j p_j out_j.
// ---------------------------------------------------------------------------
__global__ __launch_bounds__(256) void attn_kernel(
    const float* __restrict__ outm, const float* __restrict__ qm,
    const float* __restrict__ km, const float* __restrict__ vW,
    const float* __restrict__ vb_p, float* __restrict__ ctx)
{
  __shared__ __attribute__((aligned(16))) float q[256];
  __shared__ __attribute__((aligned(16))) float vv[256];
  __shared__ float p[512];
  __shared__ float red[8];

  const int blk = blockIdx.x;
  const int b = blk >> 9;
  const int i = 511 - (blk & 511);    // big-i blocks first (tail balance)
  const int tid = threadIdx.x;

  if (tid < 64) {
    ((float4*)q)[tid]  = ((const float4*)(qm + ((size_t)(b*Tt)+i)*Hh))[tid];
    ((float4*)vv)[tid] = ((const float4*)vW)[tid];
  }
  const float vb = vb_p[0];
  __syncthreads();

  // scores
  for (int j = tid; j <= i; j += 256) {
    const float* kr = km + ((size_t)(b*Tt)+j)*Hh;
    float s = 0.f;
    #pragma unroll 4
    for (int h = 0; h < 256; h += 4) {
      float4 kv = *(const float4*)(kr + h);
      float x0 = q[h+0]+kv.x, x1 = q[h+1]+kv.y, x2 = q[h+2]+kv.z, x3 = q[h+3]+kv.w;
      s += vv[h+0]*(1.f - 2.f/(1.f + __expf(2.f*x0)));
      s += vv[h+1]*(1.f - 2.f/(1.f + __expf(2.f*x1)));
      s += vv[h+2]*(1.f - 2.f/(1.f + __expf(2.f*x2)));
      s += vv[h+3]*(1.f - 2.f/(1.f + __expf(2.f*x3)));
    }
    p[j] = s + vb;
  }
  __syncthreads();

  // max
  float m = -1e30f;
  for (int j = tid; j <= i; j += 256) m = fmaxf(m, p[j]);
  #pragma unroll
  for (int off = 32; off; off >>= 1) m = fmaxf(m, __shfl_xor(m, off));
  if ((tid & 63) == 0) red[tid >> 6] = m;
  __syncthreads();
  m = fmaxf(fmaxf(red[0], red[1]), fmaxf(red[2], red[3]));

  // exp + sum
  float s = 0.f;
  for (int j = tid; j <= i; j += 256) { float e = __expf(p[j]-m); p[j] = e; s += e; }
  #pragma unroll
  for (int off = 32; off; off >>= 1) s += __shfl_xor(s, off);
  if ((tid & 63) == 0) red[4 + (tid >> 6)] = s;
  __syncthreads();
  s = red[4]+red[5]+red[6]+red[7];
  const float inv = 1.f/s;

  // ctx: thread = h
  float acc = 0.f;
  const float* op = outm + (size_t)(b*Tt)*Hh + tid;
  #pragma unroll 4
  for (int j = 0; j <= i; ++j) acc += p[j] * op[(size_t)j*Hh];
  ctx[((size_t)(b*Tt)+i)*Hh + tid] = acc*inv;
}

// ---------------------------------------------------------------------------
// FC: logits[2048,32000] = [out|ctx] @ fc_W^T + fc_b.  128x128 tile, 8x8 micro.
// ---------------------------------------------------------------------------
__global__ __launch_bounds__(256) void fc_gemm(
    const float* __restrict__ outm, const float* __restrict__ ctx,
    const float* __restrict__ W, const float* __restrict__ bias,
    float* __restrict__ Cout)
{
  __shared__ __attribute__((aligned(16))) float At[16][132];
  __shared__ __attribute__((aligned(16))) float Bt[16][132];
  const int bid = blockIdx.x;
  const int mt = bid & 15, nt = bid >> 4;
  const int m0 = mt*128, n0 = nt*128;
  const int tid = threadIdx.x;
  const int tx = tid & 15, ty = tid >> 4;   // tx: n-dir, ty: m-dir
  float acc[8][8] = {};

  for (int k0 = 0; k0 < 512; k0 += 16) {
    __syncthreads();
    #pragma unroll
    for (int r = 0; r < 2; ++r) {
      int idx = tid + r*256;
      int i = idx >> 2, c4 = idx & 3;
      int kg = k0 + c4*4;
      const float* src = (kg < 256) ? (outm + (size_t)(m0+i)*256 + kg)
                                    : (ctx  + (size_t)(m0+i)*256 + (kg-256));
      float4 v = *(const float4*)src;
      At[c4*4+0][i]=v.x; At[c4*4+1][i]=v.y; At[c4*4+2][i]=v.z; At[c4*4+3][i]=v.w;
    }
    #pragma unroll
    for (int r = 0; r < 2; ++r) {
      int idx = tid + r*256;
      int j = idx >> 2, c4 = idx & 3;
      float4 v = *(const float4*)(W + (size_t)(n0+j)*512 + k0 + c4*4);
      Bt[c4*4+0][j]=v.x; Bt[c4*4+1][j]=v.y; Bt[c4*4+2][j]=v.z; Bt[c4*4+3][j]=v.w;
    }
    __syncthreads();
    #pragma unroll
    for (int k = 0; k < 16; ++k) {
      float a[8], w[8];
      *(float4*)&a[0] = *(const float4*)&At[k][ty*8];
      *(float4*)&a[4] = *(const float4*)&At[k][ty*8+4];
      *(float4*)&w[0] = *(const float4*)&Bt[k][tx*8];
      *(float4*)&w[4] = *(const float4*)&Bt[k][tx*8+4];
      #pragma unroll
      for (int ii = 0; ii < 8; ++ii)
        #pragma unroll
        for (int jj = 0; jj < 8; ++jj)
          acc[ii][jj] += a[ii]*w[jj];
    }
  }

  float bv[8];
  *(float4*)&bv[0] = *(const float4*)(bias + n0 + tx*8);
  *(float4*)&bv[4] = *(const float4*)(bias + n0 + tx*8 + 4);
  #pragma unroll
  for (int ii = 0; ii < 8; ++ii) {
    int m = m0 + ty*8 + ii;
    float4 o0 = { acc[ii][0]+bv[0], acc[ii][1]+bv[1], acc[ii][2]+bv[2], acc[ii][3]+bv[3] };
    float4 o1 = { acc[ii][4]+bv[4], acc[ii][5]+bv[5], acc[ii][6]+bv[6], acc[ii][7]+bv[7] };
    float* dst = Cout + (size_t)m*Vv + n0 + tx*8;
    *(float4*)dst = o0;
    *(float4*)(dst+4) = o1;
  }
}

__global__ void copy_hlast(const float* __restrict__ gout, float* __restrict__ dst)
{
  int idx = blockIdx.x*256 + threadIdx.x;
  if (idx < Bb*Hh) {
    int b = idx >> 8, h = idx & 255;
    dst[idx] = gout[((size_t)(b*Tt) + (Tt-1))*Hh + h];
  }
}

extern "C" void kernel_launch(void* const* d_in, const int* in_sizes, int n_in,
                              void* d_out, int out_size, void* d_ws, size_t ws_size,
                              hipStream_t stream)
{
  const int*   x    = (const int*)  d_in[0];
  const float* h0   = (const float*)d_in[1];
  const float* embW = (const float*)d_in[2];
  const float* wih  = (const float*)d_in[3];
  const float* bih  = (const float*)d_in[4];
  const float* whh  = (const float*)d_in[5];
  const float* bhh  = (const float*)d_in[6];
  const float* awW  = (const float*)d_in[7];
  const float* awb  = (const float*)d_in[8];
  const float* auW  = (const float*)d_in[9];
  const float* aub  = (const float*)d_in[10];
  const float* avW  = (const float*)d_in[11];
  const float* avb  = (const float*)d_in[12];
  const float* fcW  = (const float*)d_in[13];
  const float* fcb  = (const float*)d_in[14];
  float* outp = (float*)d_out;

  float* ws   = (float*)d_ws;
  float* xp   = ws;                                  // 2048*768
  float* gout = xp   + (size_t)Mm*768;               // 2048*256
  float* q    = gout + (size_t)Mm*Hh;
  float* k    = q    + (size_t)Mm*Hh;
  float* ctx  = k    + (size_t)Mm*Hh;
  unsigned int* bar = (unsigned int*)(ctx + (size_t)Mm*Hh);

  hipMemsetAsync(bar, 0, 256, stream);

  dim3 g1(Mm/32, 768/64);
  gemm_small<true><<<g1, 256, 0, stream>>>(embW, x, wih, bih, xp, 768);

  gru_scan<<<32, 192, 0, stream>>>(xp, h0, whh, bhh, gout, bar);

  dim3 g3(Mm/32, 256/64);
  gemm_small<false><<<g3, 256, 0, stream>>>(gout, nullptr, awW, awb, q, 256);
  gemm_small<false><<<g3, 256, 0, stream>>>(gout, nullptr, auW, aub, k, 256);

  attn_kernel<<<Bb*Tt, 256, 0, stream>>>(gout, q, k, avW, avb, ctx);

  fc_gemm<<<16*250, 256, 0, stream>>>(gout, ctx, fcW, fcb, outp);

  copy_hlast<<<4, 256, 0, stream>>>(gout, outp + (size_t)Mm*Vv);
}

// Round 2
// 2019.419 us; speedup vs baseline: 1.8220x; 1.8220x over previous
//
#include <hip/hip_runtime.h>
#include <cstdint>
#include <cstddef>

#define Vv 32000
#define Ee 256
#define Hh 256
#define Bb 4
#define Tt 512
#define Mm (Bb*Tt)   // 2048

typedef unsigned int u32;
typedef unsigned short u16;
typedef __bf16 bf16x8 __attribute__((ext_vector_type(8)));
typedef float f32x4 __attribute__((ext_vector_type(4)));

__device__ __forceinline__ u16 f2bf(float f) {
  u32 u = __float_as_uint(f);
  u32 r = (u + 0x7FFFu + ((u >> 16) & 1u)) >> 16;   // RNE
  return (u16)r;
}

// ---------------------------------------------------------------------------
// Small GEMM: C[M,N] = A[M,256] @ W[N,256]^T + bias (A optionally gathered).
// ---------------------------------------------------------------------------
template<bool GATHER>
__global__ __launch_bounds__(256) void gemm_small(
    const float* __restrict__ A, const int* __restrict__ xidx,
    const float* __restrict__ W, const float* __restrict__ bias,
    float* __restrict__ C, int N)
{
  __shared__ float At[64][36];
  __shared__ float Wt[64][66];
  const int tid = threadIdx.x;
  const int m0 = blockIdx.x * 32;
  const int n0 = blockIdx.y * 64;
  const int tm = tid >> 5;
  const int tn = tid & 31;
  float acc[4][2] = {};

  for (int k0 = 0; k0 < 256; k0 += 64) {
    __syncthreads();
    #pragma unroll
    for (int r = 0; r < 2; ++r) {
      int idx = tid + r*256;
      int i  = idx >> 4;
      int c4 = idx & 15;
      const float* src;
      if (GATHER) src = A + (size_t)xidx[m0+i]*256 + k0 + c4*4;
      else        src = A + (size_t)(m0+i)*256 + k0 + c4*4;
      float4 v = *(const float4*)src;
      At[c4*4+0][i]=v.x; At[c4*4+1][i]=v.y; At[c4*4+2][i]=v.z; At[c4*4+3][i]=v.w;
    }
    #pragma unroll
    for (int r = 0; r < 4; ++r) {
      int idx = tid + r*256;
      int j  = idx >> 4;
      int c4 = idx & 15;
      float4 v = *(const float4*)(W + (size_t)(n0+j)*256 + k0 + c4*4);
      Wt[c4*4+0][j]=v.x; Wt[c4*4+1][j]=v.y; Wt[c4*4+2][j]=v.z; Wt[c4*4+3][j]=v.w;
    }
    __syncthreads();
    #pragma unroll 8
    for (int k = 0; k < 64; ++k) {
      float4 a = *(const float4*)&At[k][tm*4];
      float2 w = *(const float2*)&Wt[k][tn*2];
      acc[0][0] += a.x*w.x; acc[0][1] += a.x*w.y;
      acc[1][0] += a.y*w.x; acc[1][1] += a.y*w.y;
      acc[2][0] += a.z*w.x; acc[2][1] += a.z*w.y;
      acc[3][0] += a.w*w.x; acc[3][1] += a.w*w.y;
    }
  }
  #pragma unroll
  for (int i = 0; i < 4; ++i)
    #pragma unroll
    for (int j = 0; j < 2; ++j) {
      int m = m0 + tm*4 + i, n = n0 + tn*2 + j;
      C[(size_t)m*N + n] = acc[i][j] + bias[n];
    }
}

// ---------------------------------------------------------------------------
// GRU scan v2: 4 independent per-batch groups x 8 blocks. Block (b, c) owns
// rows {g*256 + c*32 + j : g<3, j<32} of w_hh (96 rows, 97.5 KB LDS).
// Sync: per-group counter; relaxed agent-scope h stores + release RMW +
// acquire poll (no threadfence).
// ---------------------------------------------------------------------------
__global__ __launch_bounds__(192) void gru_scan(
    const float* __restrict__ xp, const float* __restrict__ h0,
    const float* __restrict__ whh, const float* __restrict__ bhh,
    float* __restrict__ gout, float* __restrict__ hbuf,
    unsigned int* __restrict__ bar)
{
  __shared__ __attribute__((aligned(16))) float wl[96][260]; // stride 260: even quad spread
  __shared__ __attribute__((aligned(16))) float hl[260];
  __shared__ float dl[96];

  const int tid = threadIdx.x;
  const int bid = blockIdx.x;
  const int b = bid >> 3;    // batch
  const int c = bid & 7;     // j-chunk (32 j's)

  // load weights once: 96 rows x 64 float4 = 6144 float4 / 192 thr = 32 each
  #pragma unroll
  for (int it = 0; it < 32; ++it) {
    int idx = it*192 + tid;
    int row = idx >> 6;           // 0..95
    int c4  = idx & 63;
    int grow = (row >> 5)*256 + c*32 + (row & 31);
    float4 v = *(const float4*)(whh + (size_t)grow*256 + c4*4);
    *(float4*)&wl[row][c4*4] = v;
  }

  const int r = tid >> 1;    // 0..95
  const int q = tid & 1;
  unsigned int* barp = bar + b*64;

  float b_r = 0.f, b_z = 0.f, b_n = 0.f;
  int jg = c*32 + (tid & 31);
  if (tid < 32) { b_r = bhh[jg]; b_z = bhh[256+jg]; b_n = bhh[512+jg]; }
  __syncthreads();

  for (int t = 0; t < Tt; ++t) {
    if (tid == 0 && t > 0) {
      unsigned int tgt = 8u*(unsigned)t;
      while (__hip_atomic_load(barp, __ATOMIC_ACQUIRE, __HIP_MEMORY_SCOPE_AGENT) < tgt) {
        __builtin_amdgcn_s_sleep(1);
      }
    }
    // prefetch xp for gate threads (independent of barrier)
    float xr = 0.f, xz = 0.f, xn = 0.f;
    if (tid < 32) {
      size_t xb = ((size_t)(b*Tt) + t)*768 + jg;
      xr = xp[xb]; xz = xp[xb+256]; xn = xp[xb+512];
    }
    __syncthreads();
    if (tid < 64) {
      const float* hsrc = (t == 0) ? (h0 + b*Hh)
                                   : (hbuf + ((size_t)(b*2) + ((t-1)&1))*Hh);
      *(float4*)&hl[tid*4] = *(const float4*)(hsrc + tid*4);
    }
    __syncthreads();

    // dots: thread (r,q) covers 128 k's of row r
    float s = 0.f;
    {
      const float* wr = &wl[r][q*128];
      const float* hp = &hl[q*128];
      #pragma unroll 8
      for (int kk = 0; kk < 32; ++kk) {
        float4 w4 = *(const float4*)(wr + kk*4);
        float4 h4 = *(const float4*)(hp + kk*4);
        s += w4.x*h4.x + w4.y*h4.y + w4.z*h4.z + w4.w*h4.w;
      }
    }
    s += __shfl_xor(s, 1);
    if (q == 0) dl[r] = s;
    __syncthreads();

    if (tid < 32) {
      int j = tid;
      float dr = dl[j], dz = dl[32+j], dn = dl[64+j];
      float rr = 1.f/(1.f + __expf(-(xr + dr + b_r)));
      float zz = 1.f/(1.f + __expf(-(xz + dz + b_z)));
      float aa = xn + rr*(dn + b_n);
      float nn = 1.f - 2.f/(1.f + __expf(2.f*aa));     // tanh
      float hp = hl[jg];
      float hn = (1.f - zz)*nn + zz*hp;
      gout[((size_t)(b*Tt) + t)*Hh + jg] = hn;
      __hip_atomic_store(hbuf + ((size_t)(b*2) + (t&1))*Hh + jg, hn,
                         __ATOMIC_RELAXED, __HIP_MEMORY_SCOPE_AGENT);
    }
    if (tid == 0) {
      __hip_atomic_fetch_add(barp, 1u, __ATOMIC_RELEASE, __HIP_MEMORY_SCOPE_AGENT);
    }
  }
}

// ---------------------------------------------------------------------------
// Attention (unchanged from R1)
// ---------------------------------------------------------------------------
__global__ __launch_bounds__(256) void attn_kernel(
    const float* __restrict__ outm, const float* __restrict__ qm,
    const float* __restrict__ km, const float* __restrict__ vW,
    const float* __restrict__ vb_p, float* __restrict__ ctx)
{
  __shared__ __attribute__((aligned(16))) float q[256];
  __shared__ __attribute__((aligned(16))) float vv[256];
  __shared__ float p[512];
  __shared__ float red[8];

  const int blk = blockIdx.x;
  const int b = blk >> 9;
  const int i = 511 - (blk & 511);
  const int tid = threadIdx.x;

  if (tid < 64) {
    ((float4*)q)[tid]  = ((const float4*)(qm + ((size_t)(b*Tt)+i)*Hh))[tid];
    ((float4*)vv)[tid] = ((const float4*)vW)[tid];
  }
  const float vb = vb_p[0];
  __syncthreads();

  for (int j = tid; j <= i; j += 256) {
    const float* kr = km + ((size_t)(b*Tt)+j)*Hh;
    float s = 0.f;
    #pragma unroll 4
    for (int h = 0; h < 256; h += 4) {
      float4 kv = *(const float4*)(kr + h);
      float x0 = q[h+0]+kv.x, x1 = q[h+1]+kv.y, x2 = q[h+2]+kv.z, x3 = q[h+3]+kv.w;
      s += vv[h+0]*(1.f - 2.f/(1.f + __expf(2.f*x0)));
      s += vv[h+1]*(1.f - 2.f/(1.f + __expf(2.f*x1)));
      s += vv[h+2]*(1.f - 2.f/(1.f + __expf(2.f*x2)));
      s += vv[h+3]*(1.f - 2.f/(1.f + __expf(2.f*x3)));
    }
    p[j] = s + vb;
  }
  __syncthreads();

  float m = -1e30f;
  for (int j = tid; j <= i; j += 256) m = fmaxf(m, p[j]);
  #pragma unroll
  for (int off = 32; off; off >>= 1) m = fmaxf(m, __shfl_xor(m, off));
  if ((tid & 63) == 0) red[tid >> 6] = m;
  __syncthreads();
  m = fmaxf(fmaxf(red[0], red[1]), fmaxf(red[2], red[3]));

  float s = 0.f;
  for (int j = tid; j <= i; j += 256) { float e = __expf(p[j]-m); p[j] = e; s += e; }
  #pragma unroll
  for (int off = 32; off; off >>= 1) s += __shfl_xor(s, off);
  if ((tid & 63) == 0) red[4 + (tid >> 6)] = s;
  __syncthreads();
  s = red[4]+red[5]+red[6]+red[7];
  const float inv = 1.f/s;

  float acc = 0.f;
  const float* op = outm + (size_t)(b*Tt)*Hh + tid;
  #pragma unroll 4
  for (int j = 0; j <= i; ++j) acc += p[j] * op[(size_t)j*Hh];
  ctx[((size_t)(b*Tt)+i)*Hh + tid] = acc*inv;
}

// ---------------------------------------------------------------------------
// fp32 -> bf16 converters
// ---------------------------------------------------------------------------
__global__ __launch_bounds__(256) void conv_w_bf16(
    const float* __restrict__ src, u16* __restrict__ dst, int n8)
{
  int i = blockIdx.x*256 + threadIdx.x;
  if (i < n8) {
    float4 a = ((const float4*)src)[i*2];
    float4 b = ((const float4*)src)[i*2+1];
    uint4 o;
    o.x = (u32)f2bf(a.x) | ((u32)f2bf(a.y) << 16);
    o.y = (u32)f2bf(a.z) | ((u32)f2bf(a.w) << 16);
    o.z = (u32)f2bf(b.x) | ((u32)f2bf(b.y) << 16);
    o.w = (u32)f2bf(b.z) | ((u32)f2bf(b.w) << 16);
    ((uint4*)dst)[i] = o;
  }
}

__global__ __launch_bounds__(256) void conv_comb_bf16(
    const float* __restrict__ gout, const float* __restrict__ ctx,
    u16* __restrict__ dst)
{
  int i = blockIdx.x*256 + threadIdx.x;     // 131072 groups of 8
  int m  = i >> 6;
  int kg = (i & 63) * 8;
  const float* src = (kg < 256) ? (gout + (size_t)m*256 + kg)
                                : (ctx  + (size_t)m*256 + kg - 256);
  float4 a = *(const float4*)src;
  float4 b = *(const float4*)(src + 4);
  uint4 o;
  o.x = (u32)f2bf(a.x) | ((u32)f2bf(a.y) << 16);
  o.y = (u32)f2bf(a.z) | ((u32)f2bf(a.w) << 16);
  o.z = (u32)f2bf(b.x) | ((u32)f2bf(b.y) << 16);
  o.w = (u32)f2bf(b.z) | ((u32)f2bf(b.w) << 16);
  ((uint4*)dst)[i] = o;
}

// ---------------------------------------------------------------------------
// FC MFMA: logits[2048,32000] = comb_bf16 @ Wb^T + fc_b.
// 128x128 tile, BK=32, 4 waves each computing a 64x64 quadrant via 4x4 grid
// of 16x16x32 MFMA. global_load_lds width-16 staging.
// ---------------------------------------------------------------------------
__global__ __launch_bounds__(256) void fc_mfma(
    const u16* __restrict__ Ab, const u16* __restrict__ Wb,
    const float* __restrict__ bias, float* __restrict__ C)
{
  __shared__ __attribute__((aligned(16))) u16 As[128*32];
  __shared__ __attribute__((aligned(16))) u16 Bs[128*32];
  const int bid = blockIdx.x;
  const int mt = bid & 15, nt = bid >> 4;
  const int m0 = mt*128, n0 = nt*128;
  const int tid = threadIdx.x;
  const int wave = tid >> 6, lane = tid & 63;

  f32x4 acc[4][4];
  #pragma unroll
  for (int i = 0; i < 4; ++i)
    #pragma unroll
    for (int j = 0; j < 4; ++j)
      acc[i][j] = (f32x4){0.f, 0.f, 0.f, 0.f};

  const int wm = (wave & 1)*64;   // wave m-quadrant
  const int wn = (wave >> 1)*64;  // wave n-quadrant
  const int frow = lane & 15;     // fragment row (m or n within 16-tile)
  const int fk   = (lane >> 4)*8; // fragment k offset

  for (int k0 = 0; k0 < 512; k0 += 32) {
    __syncthreads();
    #pragma unroll
    for (int i = 0; i < 2; ++i) {
      int ebase = wave*1024 + i*512;      // ushort index, wave-uniform
      int e = ebase + lane*8;
      int row = e >> 5, col = e & 31;
      __builtin_amdgcn_global_load_lds(
          (const __attribute__((address_space(1))) u32*)(Ab + (size_t)(m0+row)*512 + k0 + col),
          (__attribute__((address_space(3))) u32*)(As + ebase), 16, 0, 0);
      __builtin_amdgcn_global_load_lds(
          (const __attribute__((address_space(1))) u32*)(Wb + (size_t)(n0+row)*512 + k0 + col),
          (__attribute__((address_space(3))) u32*)(Bs + ebase), 16, 0, 0);
    }
    __syncthreads();

    bf16x8 af[4], bfr[4];
    #pragma unroll
    for (int mi = 0; mi < 4; ++mi)
      af[mi] = *(const bf16x8*)&As[(wm + mi*16 + frow)*32 + fk];
    #pragma unroll
    for (int ni = 0; ni < 4; ++ni)
      bfr[ni] = *(const bf16x8*)&Bs[(wn + ni*16 + frow)*32 + fk];
    #pragma unroll
    for (int mi = 0; mi < 4; ++mi)
      #pragma unroll
      for (int ni = 0; ni < 4; ++ni)
        acc[mi][ni] = __builtin_amdgcn_mfma_f32_16x16x32_bf16(af[mi], bfr[ni], acc[mi][ni], 0, 0, 0);
  }

  // epilogue: C[row=(lane>>4)*4+reg][col=lane&15] per 16x16 tile
  const int coln = lane & 15, rq = (lane >> 4)*4;
  #pragma unroll
  for (int ni = 0; ni < 4; ++ni) {
    int n = n0 + wn + ni*16 + coln;
    float bb = bias[n];
    #pragma unroll
    for (int mi = 0; mi < 4; ++mi) {
      int mbase = m0 + wm + mi*16 + rq;
      #pragma unroll
      for (int r2 = 0; r2 < 4; ++r2)
        C[(size_t)(mbase + r2)*Vv + n] = acc[mi][ni][r2] + bb;
    }
  }
}

__global__ void copy_hlast(const float* __restrict__ gout, float* __restrict__ dst)
{
  int idx = blockIdx.x*256 + threadIdx.x;
  if (idx < Bb*Hh) {
    int b = idx >> 8, h = idx & 255;
    dst[idx] = gout[((size_t)(b*Tt) + (Tt-1))*Hh + h];
  }
}

extern "C" void kernel_launch(void* const* d_in, const int* in_sizes, int n_in,
                              void* d_out, int out_size, void* d_ws, size_t ws_size,
                              hipStream_t stream)
{
  const int*   x    = (const int*)  d_in[0];
  const float* h0   = (const float*)d_in[1];
  const float* embW = (const float*)d_in[2];
  const float* wih  = (const float*)d_in[3];
  const float* bih  = (const float*)d_in[4];
  const float* whh  = (const float*)d_in[5];
  const float* bhh  = (const float*)d_in[6];
  const float* awW  = (const float*)d_in[7];
  const float* awb  = (const float*)d_in[8];
  const float* auW  = (const float*)d_in[9];
  const float* aub  = (const float*)d_in[10];
  const float* avW  = (const float*)d_in[11];
  const float* avb  = (const float*)d_in[12];
  const float* fcW  = (const float*)d_in[13];
  const float* fcb  = (const float*)d_in[14];
  float* outp = (float*)d_out;

  float* ws   = (float*)d_ws;
  float* xp   = ws;                                  // 2048*768
  float* gout = xp   + (size_t)Mm*768;               // 2048*256
  float* q    = gout + (size_t)Mm*Hh;
  float* k    = q    + (size_t)Mm*Hh;
  float* ctx  = k    + (size_t)Mm*Hh;
  float* hbuf = ctx  + (size_t)Mm*Hh;                // 4*2*256 = 2048
  unsigned int* bar = (unsigned int*)(hbuf + 2048);  // 256 u32
  u16* comb = (u16*)(bar + 256);                     // 2048*512 bf16
  u16* Wb   = comb + (size_t)Mm*512;                 // 32000*512 bf16

  hipMemsetAsync(bar, 0, 1024, stream);

  dim3 g1(Mm/32, 768/64);
  gemm_small<true><<<g1, 256, 0, stream>>>(embW, x, wih, bih, xp, 768);

  conv_w_bf16<<<8000, 256, 0, stream>>>(fcW, Wb, Vv*512/8);

  gru_scan<<<32, 192, 0, stream>>>(xp, h0, whh, bhh, gout, hbuf, bar);

  dim3 g3(Mm/32, 256/64);
  gemm_small<false><<<g3, 256, 0, stream>>>(gout, nullptr, awW, awb, q, 256);
  gemm_small<false><<<g3, 256, 0, stream>>>(gout, nullptr, auW, aub, k, 256);

  attn_kernel<<<Bb*Tt, 256, 0, stream>>>(gout, q, k, avW, avb, ctx);

  conv_comb_bf16<<<512, 256, 0, stream>>>(gout, ctx, comb);

  fc_mfma<<<16*250, 256, 0, stream>>>(comb, Wb, fcb, outp);

  copy_hlast<<<4, 256, 0, stream>>>(gout, outp + (size_t)Mm*Vv);
}